// Round 13
// baseline (773.131 us; speedup 1.0000x reference)
//
#include <hip/hip_runtime.h>
#include <hip/hip_bf16.h>

// Problem constants
#define TT   128
#define BB   256
#define MM   512
#define GG   2560
#define K1P  960   // 940 padded to 960 (15 * 64)

typedef __attribute__((ext_vector_type(8))) short bf16x8;
typedef __attribute__((ext_vector_type(4))) short bf16x4;
typedef __attribute__((ext_vector_type(4))) float f32x4;

__device__ __forceinline__ float bf2f(unsigned short u){
  union { unsigned u; float f; } v; v.u = ((unsigned)u) << 16; return v.f;
}
__device__ __forceinline__ unsigned short f2bf(float f){
  union { float f; unsigned u; } v; v.f = f;
  unsigned r = v.u + 0x7fffu + ((v.u >> 16) & 1u);
  return (unsigned short)(r >> 16);
}
__device__ __forceinline__ float sigmoidf_(float x){ return 1.f/(1.f + __expf(-x)); }
__device__ __forceinline__ float tanhf_(float x){
  x = fminf(15.f, fmaxf(-15.f, x));
  float e = __expf(2.f*x);
  return (e - 1.f)/(e + 1.f);
}

// ---- MALL-coherent (sc0 sc1) helpers — the ONLY replay-safe cross-block
// exchange on this part (R5/R6 proven over graph replays).
// Session findings (do not revisit):
//   R8 : unscoped atomic + sc0 poll -> livelock (atomics execute memory-side)
//   R10: sc0 flag separate from data -> race
//   R11: sc0 tagged-in-data         -> race
//   R12: sc0 data + MALL barrier    -> INTERMITTENT race (failed post-timing)
// Conclusion: vmcnt-ack of an sc0 store != cross-CU visibility in XCD L2.
__device__ __forceinline__ void store_coh4(void* p, unsigned v){
  asm volatile("global_store_dword %0, %1, off sc0 sc1" :: "v"(p), "v"(v) : "memory");
}
__device__ __forceinline__ unsigned load_coh_u32(const unsigned* p){
  unsigned r;
  asm volatile("global_load_dword %0, %1, off sc0 sc1" : "=v"(r) : "v"(p) : "memory");
  asm volatile("s_waitcnt vmcnt(0)" ::: "memory");
  return r;
}
__device__ __forceinline__ bf16x8 load_h16(const void* p){
  bf16x8 r;
  asm volatile("global_load_dwordx4 %0, %1, off sc0 sc1" : "=v"(r) : "v"(p) : "memory");
  return r;
}
__device__ __forceinline__ void store_h32(void* p, unsigned v){
  asm volatile("global_store_dword %0, %1, off sc0 sc1" :: "v"(p), "v"(v) : "memory");
}

// async global->LDS, 16B per lane; LDS dest = wave-uniform base + lane*16
__device__ __forceinline__ void gll16(const unsigned short* g, unsigned short* l){
  __builtin_amdgcn_global_load_lds(
      (const __attribute__((address_space(1))) void*)(g),
      (__attribute__((address_space(3))) void*)(l),
      16, 0, 0);
}

// ---------------- staging kernels ----------------

__global__ __launch_bounds__(256) void stage_a(const float* __restrict__ word,
                                               const float* __restrict__ tag,
                                               const float* __restrict__ rel,
                                               const float* __restrict__ kin,
                                               unsigned short* __restrict__ A){
  long id = (long)blockIdx.x * 256 + threadIdx.x;     // chunk over 32768*120
  int row = (int)(id / 120);
  int c8  = (int)(id % 120) * 8;
  bf16x8 o;
  #pragma unroll
  for (int j = 0; j < 8; ++j){
    int col = c8 + j; float v;
    if      (col < 300) v = word[(long)row*300 + col];
    else if (col < 364) v = tag [(long)row*64  + col-300];
    else if (col < 428) v = rel [(long)row*64  + col-364];
    else if (col < 940) v = kin [(long)row*512 + col-428];
    else v = 0.f;
    o[j] = (short)f2bf(v);
  }
  *reinterpret_cast<bf16x8*>(A + (long)row*K1P + c8) = o;
}

__global__ __launch_bounds__(256) void stage_wt(const float* __restrict__ Ww,
                                                const float* __restrict__ Wt,
                                                const float* __restrict__ Wr,
                                                const float* __restrict__ Wk,
                                                unsigned short* __restrict__ WT){
  long id = (long)blockIdx.x * 256 + threadIdx.x;   // 2560*960
  int kk = (int)(id % K1P);
  int n  = (int)(id / K1P);
  float v;
  if      (kk < 300) v = Ww[(long)kk*GG + n];
  else if (kk < 364) v = Wt[(long)(kk-300)*GG + n];
  else if (kk < 428) v = Wr[(long)(kk-364)*GG + n];
  else if (kk < 940) v = Wk[(long)(kk-428)*GG + n];
  else v = 0.f;
  WT[(long)n*K1P + kk] = f2bf(v);
}

__global__ __launch_bounds__(256) void stage_wht(const float* __restrict__ Wh,
                                                 unsigned short* __restrict__ WhT){
  long id = (long)blockIdx.x * 256 + threadIdx.x;   // 2560*512
  int kk = (int)(id % MM);
  int n  = (int)(id / MM);
  WhT[(long)n*MM + kk] = f2bf(Wh[(long)kk*GG + n]);
}

__global__ __launch_bounds__(256) void init_h(const float* __restrict__ h0,
                                              unsigned short* __restrict__ hb){
  int id = blockIdx.x * 256 + threadIdx.x;          // 131072
  hb[id] = f2bf(h0[id]);
}

// ---------------- xp GEMM: 128x128 tile, BK=64, swizzled LDS ----------------
// (validated in R12 first-launch: absmax 0.03125; deterministic)
// LDS [128 rows][64 k] bf16. Content XOR-swizzled: LDS(R,ybyte) holds global
// col-bytes ybyte ^ ((R&7)<<4). Staging keeps gll16's LINEAR dest and
// pre-swizzles the GLOBAL source column (both-sides-or-neither rule).
// Reads apply the same XOR -> uniform 16B-slot bank spread.
// Grid: 1D 5120, XCD-bijective swizzle (5120%8==0) for B-panel L2 reuse.
__global__ __launch_bounds__(256) void gemm_xp(const unsigned short* __restrict__ A,
                                               const unsigned short* __restrict__ WT,
                                               const float* __restrict__ bias,
                                               unsigned short* __restrict__ XP){
  __shared__ unsigned short As[128*64];   // 16 KB
  __shared__ unsigned short Bs[128*64];   // 16 KB
  const int tid  = threadIdx.x;
  const int wave = tid >> 6, lane = tid & 63;
  const int wr   = wave >> 1, wc = wave & 1;
  const int lrow = lane & 15, lhi = lane >> 4;

  const int swz = (blockIdx.x & 7) * (5120 / 8) + (blockIdx.x >> 3);
  const long row0 = (long)(swz & 255) * 128;        // M-tile (t,b rows)
  const long col0 = (long)(swz >> 8) * 128;         // N-tile (gate cols)

  const int srow = wave*8 + (lane >> 3);
  const int scol = (((lane & 7) ^ (lane >> 3)) * 8);
  const unsigned short* gaB = A  + (row0 + srow)*K1P + scol;
  const unsigned short* gbB = WT + (col0 + srow)*K1P + scol;

  f32x4 acc[4][4] = {};
  for (int ks = 0; ks < 15; ++ks){
    const int k0 = ks * 64;
    __syncthreads();                    // prev iter's LDS reads done
    #pragma unroll
    for (int s = 0; s < 4; ++s){
      gll16(gaB + (long)s*32*K1P + k0, As + (s*32 + wave*8)*64);
      gll16(gbB + (long)s*32*K1P + k0, Bs + (s*32 + wave*8)*64);
    }
    __syncthreads();                    // vmcnt(0) drain -> tiles ready
    bf16x8 af[2][4], bfr[2][4];
    const int sx = (lrow & 7) * 8;      // read-side XOR (elements)
    #pragma unroll
    for (int kk = 0; kk < 2; ++kk){
      #pragma unroll
      for (int mi = 0; mi < 4; ++mi)
        af[kk][mi] = *reinterpret_cast<const bf16x8*>(
            As + (wr*64 + mi*16 + lrow)*64 + ((kk*32 + lhi*8) ^ sx));
      #pragma unroll
      for (int ni = 0; ni < 4; ++ni)
        bfr[kk][ni] = *reinterpret_cast<const bf16x8*>(
            Bs + (wc*64 + ni*16 + lrow)*64 + ((kk*32 + lhi*8) ^ sx));
    }
    #pragma unroll
    for (int kk = 0; kk < 2; ++kk)
      #pragma unroll
      for (int mi = 0; mi < 4; ++mi)
        #pragma unroll
        for (int ni = 0; ni < 4; ++ni)
          acc[mi][ni] = __builtin_amdgcn_mfma_f32_16x16x32_bf16(af[kk][mi], bfr[kk][ni], acc[mi][ni], 0, 0, 0);
  }
  // epilogue (proven): + bias, XP stored [T][G][B]
  const int t     = (int)(row0 >> 8);
  const int brow0 = (int)(row0 & 255);
  #pragma unroll
  for (int ni = 0; ni < 4; ++ni){
    const int col = (int)col0 + wc*64 + ni*16 + lrow;
    const float bv = bias[col];
    #pragma unroll
    for (int mi = 0; mi < 4; ++mi){
      const int b4 = brow0 + wr*64 + mi*16 + lhi*4;
      bf16x4 pk;
      #pragma unroll
      for (int j = 0; j < 4; ++j) pk[j] = (short)f2bf(acc[mi][ni][j] + bv);
      *reinterpret_cast<bf16x4*>(XP + ((long)t*GG + col)*BB + b4) = pk;
    }
  }
}

// ---------------- fused persistent recurrence (R5-proven protocol) ----------
// grid 256 x 256. Block = (bt 0..7) x (mc 0..31): batch rows [bt*32,+32),
// m-cols [mc*16,+16), all 5 gates. K-split waves: wave w owns k-quarter.
// ALL cross-block traffic at MALL scope (sc0 sc1) — the only protocol that
// survived graph-replay validation. Barrier: MALL atomic ctr + tid0 poll +
// syncthreads broadcast (R5). Only post-R5 change: running-offset prefetch.
__global__ __launch_bounds__(256, 1) void lstm_fused(const unsigned short* __restrict__ XP,
                                                     const float* __restrict__ q,
                                                     const unsigned short* __restrict__ WhT,
                                                     const float* __restrict__ c0,
                                                     unsigned short* __restrict__ hb0,
                                                     unsigned short* __restrict__ hb1,
                                                     float* __restrict__ out,
                                                     unsigned* __restrict__ cnts){
  __shared__ float Part[4][5][2][16][20];        // [w][gate][rt][m][b pad20] 51.2 KB
  const int tid  = threadIdx.x;
  const int w    = tid >> 6, lane = tid & 63;
  const int lrow = lane & 15, lhi = lane >> 4;
  const int bt = blockIdx.x >> 5, mc = blockIdx.x & 31;
  const int b0 = bt * 32, m0 = mc * 16;
  unsigned* cnt = cnts + bt * 64;                // per-bt counter, own cacheline

  // this wave's k-quarter of Wh for all 5 gates (80 VGPR)
  bf16x8 Breg[5][4];
  #pragma unroll
  for (int g = 0; g < 5; ++g)
    #pragma unroll
    for (int kf = 0; kf < 4; ++kf)
      Breg[g][kf] = *reinterpret_cast<const bf16x8*>(
          WhT + (long)(g*MM + m0 + lrow)*MM + w*128 + kf*32 + lhi*8);

  // update-phase mapping: 2 states per thread
  const int bl = tid >> 3, mi2 = (tid & 7) * 2;
  const int rt2 = bl >> 4, brow = bl & 15;
  const int gb = b0 + bl, gm = m0 + mi2;
  float cx = c0[(long)gb*MM + gm];
  float cy = c0[(long)gb*MM + gm + 1];

  // precomputed per-thread offsets; running t-offsets (saves 64-bit muls/step)
  long oj[5];
  #pragma unroll
  for (int j = 0; j < 5; ++j) oj[j] = ((long)j*MM + gm)*BB + gb;
  const long qb0 = (long)gb*MM + gm;
  const long XSTEP = (long)GG*BB, QSTEP = (long)BB*MM;

  // prefetch t=0 xp/q
  unsigned short xv[5][2]; float qx, qy;
  #pragma unroll
  for (int j = 0; j < 5; ++j){
    xv[j][0] = XP[oj[j]];
    xv[j][1] = XP[oj[j] + BB];
  }
  qx = q[qb0];
  qy = q[qb0 + 1];
  long xo = XSTEP, qo = QSTEP;                   // offsets for t=1 prefetch

  for (int t = 0; t < TT; ++t){
    const unsigned short* hc = (t & 1) ? hb1 : hb0;
    unsigned short*       hn = (t & 1) ? hb0 : hb1;

    // issue h fragment loads straight to regs, kf-major (oldest = kf0 pair)
    bf16x8 af[2][4];
    #pragma unroll
    for (int kf = 0; kf < 4; ++kf)
      #pragma unroll
      for (int rt = 0; rt < 2; ++rt)
        af[rt][kf] = load_h16(hc + (long)(b0 + rt*16 + lrow)*MM + w*128 + kf*32 + lhi*8);

    // MFMA with counted waits; SB brackets stop MFMA hoisting past waits
    f32x4 acc[5][2] = {};
    #pragma unroll
    for (int kf = 0; kf < 4; ++kf){
      __builtin_amdgcn_sched_barrier(0);
      if      (kf == 0) asm volatile("s_waitcnt vmcnt(6)" ::: "memory");
      else if (kf == 1) asm volatile("s_waitcnt vmcnt(4)" ::: "memory");
      else if (kf == 2) asm volatile("s_waitcnt vmcnt(2)" ::: "memory");
      else              asm volatile("s_waitcnt vmcnt(0)" ::: "memory");
      __builtin_amdgcn_sched_barrier(0);
      #pragma unroll
      for (int rt = 0; rt < 2; ++rt)
        #pragma unroll
        for (int g = 0; g < 5; ++g)
          acc[g][rt] = __builtin_amdgcn_mfma_f32_16x16x32_bf16(af[rt][kf], Breg[g][kf], acc[g][rt], 0, 0, 0);
    }

    // publish k-partials (D: col=m=lrow, row=b=lhi*4+j -> [m][b] contiguous x4)
    #pragma unroll
    for (int g = 0; g < 5; ++g)
      #pragma unroll
      for (int rt = 0; rt < 2; ++rt)
        *reinterpret_cast<f32x4*>(&Part[w][g][rt][lrow][lhi*4]) = acc[g][rt];
    __syncthreads();                               // syncA: Part ready

    // k-reduction + gates for this thread's 2 states
    float gv[5][2];
    #pragma unroll
    for (int g = 0; g < 5; ++g)
      #pragma unroll
      for (int x = 0; x < 2; ++x)
        gv[g][x] = Part[0][g][rt2][mi2+x][brow] + Part[1][g][rt2][mi2+x][brow]
                 + Part[2][g][rt2][mi2+x][brow] + Part[3][g][rt2][mi2+x][brow]
                 + bf2f(xv[g][x]);

    float hx, hy;
    {
      const float i_ = sigmoidf_(gv[0][0]);
      const float fd = sigmoidf_(gv[1][0]);
      const float fl = sigmoidf_(gv[2][0]);
      const float o_ = sigmoidf_(gv[3][0]);
      const float u_ = tanhf_(gv[4][0]);
      const float cn = i_*u_ + fd*qx + fl*cx;
      cx = cn; hx = o_*tanhf_(cn);
    }
    {
      const float i_ = sigmoidf_(gv[0][1]);
      const float fd = sigmoidf_(gv[1][1]);
      const float fl = sigmoidf_(gv[2][1]);
      const float o_ = sigmoidf_(gv[3][1]);
      const float u_ = tanhf_(gv[4][1]);
      const float cn = i_*u_ + fd*qy + fl*cy;
      cy = cn; hy = o_*tanhf_(cn);
    }

    // store h EARLY (MALL scope) so the drain starts sooner
    const unsigned hv = (unsigned)f2bf(hx) | ((unsigned)f2bf(hy) << 16);
    if (t < TT - 1){
      store_h32(hn + (long)gb*MM + gm, hv);
    } else {
      out[(long)gb*1024 + gm]           = hx;
      out[(long)gb*1024 + gm + 1]       = hy;
      out[(long)gb*1024 + 512 + gm]     = cx;
      out[(long)gb*1024 + 512 + gm + 1] = cy;
    }

    // prefetch next step's xp/q (fills the barrier wait) — running offsets
    if (t < TT - 1){
      #pragma unroll
      for (int j = 0; j < 5; ++j){
        xv[j][0] = XP[xo + oj[j]];
        xv[j][1] = XP[xo + oj[j] + BB];
      }
      qx = q[qo + qb0];
      qy = q[qo + qb0 + 1];
      xo += XSTEP; qo += QSTEP;
    }

    // per-bt barrier (R5): syncB drains all h stores to MALL before arrive;
    // tid0 polls; syncC broadcasts.
    if (t != TT - 1){
      __syncthreads();                             // syncB
      if (tid == 0){
        __hip_atomic_fetch_add(cnt, 1u, __ATOMIC_RELAXED, __HIP_MEMORY_SCOPE_AGENT);
        const unsigned target = (unsigned)(t + 1) * 32u;
        unsigned spins = 0;
        while (load_coh_u32(cnt) < target){
          __builtin_amdgcn_s_sleep(1);
          if (++spins > (1u << 20)) break;         // safety valve
        }
      }
      __syncthreads();                             // syncC: release all waves
    }
  }
}

extern "C" void kernel_launch(void* const* d_in, const int* in_sizes, int n_in,
                              void* d_out, int out_size, void* d_ws, size_t ws_size,
                              hipStream_t stream){
  (void)in_sizes; (void)n_in; (void)out_size; (void)ws_size;
  const float* word = (const float*)d_in[0];
  const float* tag  = (const float*)d_in[1];
  const float* rel  = (const float*)d_in[2];
  const float* kin  = (const float*)d_in[3];
  const float* q    = (const float*)d_in[4];
  const float* h0   = (const float*)d_in[5];
  const float* c0   = (const float*)d_in[6];
  const float* Ww   = (const float*)d_in[7];
  const float* Wt   = (const float*)d_in[8];
  const float* Wr   = (const float*)d_in[9];
  const float* Wk   = (const float*)d_in[10];
  const float* Wh   = (const float*)d_in[11];
  const float* bias = (const float*)d_in[12];
  float* out = (float*)d_out;

  char* ws = (char*)d_ws;
  size_t off = 0;
  auto alloc = [&](size_t bytes)->void*{
    void* p = ws + off; off = (off + bytes + 255) & ~(size_t)255; return p;
  };
  unsigned short* Abf = (unsigned short*)alloc((size_t)TT*BB*K1P*2);   // 62.9 MB
  unsigned short* WT  = (unsigned short*)alloc((size_t)GG*K1P*2);      // 4.9 MB
  unsigned short* WhT = (unsigned short*)alloc((size_t)GG*MM*2);       // 2.6 MB
  unsigned short* XP  = (unsigned short*)alloc((size_t)TT*BB*GG*2);    // 167.8 MB
  unsigned short* hb0 = (unsigned short*)alloc((size_t)BB*MM*2);
  unsigned short* hb1 = (unsigned short*)alloc((size_t)BB*MM*2);
  unsigned*       cnt = (unsigned*)alloc(8 * 64 * sizeof(unsigned));   // per-bt counters

  hipMemsetAsync(cnt, 0, 8 * 64 * sizeof(unsigned), stream);

  stage_a  <<<dim3((TT*BB*(K1P/8) + 255)/256), 256, 0, stream>>>(word, tag, rel, kin, Abf);
  stage_wt <<<dim3((GG*K1P + 255)/256),        256, 0, stream>>>(Ww, Wt, Wr, Wk, WT);
  stage_wht<<<dim3((GG*MM + 255)/256),         256, 0, stream>>>(Wh, WhT);
  init_h   <<<dim3((BB*MM + 255)/256),         256, 0, stream>>>(h0, hb0);

  gemm_xp<<<dim3(5120), 256, 0, stream>>>(Abf, WT, bias, XP);

  lstm_fused<<<dim3(256), 256, 0, stream>>>(XP, q, WhT, c0, hb0, hb1, out, cnt);
}

// Round 14
// 756.456 us; speedup vs baseline: 1.0220x; 1.0220x over previous
//
#include <hip/hip_runtime.h>
#include <hip/hip_bf16.h>

// Problem constants
#define TT   128
#define BB   256
#define MM   512
#define GG   2560
#define K1P  1024  // 940 padded to 1024 (4 waves x 8 chunks x 32)

typedef __attribute__((ext_vector_type(8))) short bf16x8;
typedef __attribute__((ext_vector_type(4))) short bf16x4;
typedef __attribute__((ext_vector_type(4))) float f32x4;

__device__ __forceinline__ float bf2f(unsigned short u){
  union { unsigned u; float f; } v; v.u = ((unsigned)u) << 16; return v.f;
}
__device__ __forceinline__ unsigned short f2bf(float f){
  union { float f; unsigned u; } v; v.f = f;
  unsigned r = v.u + 0x7fffu + ((v.u >> 16) & 1u);
  return (unsigned short)(r >> 16);
}
__device__ __forceinline__ float sigmoidf_(float x){ return 1.f/(1.f + __expf(-x)); }
__device__ __forceinline__ float tanhf_(float x){
  x = fminf(15.f, fmaxf(-15.f, x));
  float e = __expf(2.f*x);
  return (e - 1.f)/(e + 1.f);
}

// ---- MALL-coherent (sc0 sc1) helpers — the ONLY replay-safe cross-block
// exchange on this part. Session findings (do not revisit):
//   R8 : unscoped atomic + sc0 poll -> livelock
//   R10: sc0 flag separate from data -> race
//   R11: sc0 tagged-in-data         -> race
//   R12: sc0 data + MALL barrier    -> INTERMITTENT race (failed post-timing)
// Conclusion: vmcnt-ack of an sc0 store != cross-CU visibility in XCD L2.
__device__ __forceinline__ unsigned load_coh_u32(const unsigned* p){
  unsigned r;
  asm volatile("global_load_dword %0, %1, off sc0 sc1" : "=v"(r) : "v"(p) : "memory");
  asm volatile("s_waitcnt vmcnt(0)" ::: "memory");
  return r;
}
__device__ __forceinline__ bf16x8 load_h16(const void* p){
  bf16x8 r;
  asm volatile("global_load_dwordx4 %0, %1, off sc0 sc1" : "=v"(r) : "v"(p) : "memory");
  return r;
}
__device__ __forceinline__ void store_h32(void* p, unsigned v){
  asm volatile("global_store_dword %0, %1, off sc0 sc1" :: "v"(p), "v"(v) : "memory");
}
// plain cached 16B load as asm so OUR vmcnt bookkeeping stays exact
// (compiler-invisible loads + manual counted waits must not mix with
// compiler-tracked loads in the same window)
__device__ __forceinline__ bf16x8 ldg16(const void* p){
  bf16x8 r;
  asm volatile("global_load_dwordx4 %0, %1, off" : "=v"(r) : "v"(p) : "memory");
  return r;
}

// ---------------- staging kernels ----------------

__global__ __launch_bounds__(256) void stage_a(const float* __restrict__ word,
                                               const float* __restrict__ tag,
                                               const float* __restrict__ rel,
                                               const float* __restrict__ kin,
                                               unsigned short* __restrict__ A){
  long id = (long)blockIdx.x * 256 + threadIdx.x;     // chunk over 32768*128
  int row = (int)(id >> 7);
  int c8  = (int)(id & 127) * 8;
  bf16x8 o;
  #pragma unroll
  for (int j = 0; j < 8; ++j){
    int col = c8 + j; float v;
    if      (col < 300) v = word[(long)row*300 + col];
    else if (col < 364) v = tag [(long)row*64  + col-300];
    else if (col < 428) v = rel [(long)row*64  + col-364];
    else if (col < 940) v = kin [(long)row*512 + col-428];
    else v = 0.f;
    o[j] = (short)f2bf(v);
  }
  *reinterpret_cast<bf16x8*>(A + (long)row*K1P + c8) = o;
}

__global__ __launch_bounds__(256) void stage_wt(const float* __restrict__ Ww,
                                                const float* __restrict__ Wt,
                                                const float* __restrict__ Wr,
                                                const float* __restrict__ Wk,
                                                unsigned short* __restrict__ WT){
  long id = (long)blockIdx.x * 256 + threadIdx.x;   // 2560*1024
  int kk = (int)(id & 1023);
  int n  = (int)(id >> 10);
  float v;
  if      (kk < 300) v = Ww[(long)kk*GG + n];
  else if (kk < 364) v = Wt[(long)(kk-300)*GG + n];
  else if (kk < 428) v = Wr[(long)(kk-364)*GG + n];
  else if (kk < 940) v = Wk[(long)(kk-428)*GG + n];
  else v = 0.f;
  WT[(long)n*K1P + kk] = f2bf(v);
}

__global__ __launch_bounds__(256) void stage_wht(const float* __restrict__ Wh,
                                                 unsigned short* __restrict__ WhT){
  long id = (long)blockIdx.x * 256 + threadIdx.x;   // 2560*512
  int kk = (int)(id % MM);
  int n  = (int)(id / MM);
  WhT[(long)n*MM + kk] = f2bf(Wh[(long)kk*GG + n]);
}

__global__ __launch_bounds__(256) void init_h(const float* __restrict__ h0,
                                              unsigned short* __restrict__ hb){
  int id = blockIdx.x * 256 + threadIdx.x;          // 131072
  hb[id] = f2bf(h0[id]);
}

// ---------------- fused persistent recurrence + in-loop xp GEMM -------------
// grid 256 x 256. Block = (bt 0..7) x (mc 0..31): batch rows [bt*32,+32),
// m-cols [mc*16,+16), all 5 gates. K-split waves: wave w owns k-quarter of
// BOTH reductions: Wh (K=512 -> 128/wave) and W=[Ww;Wt;Wr;Wk] (K=1024 ->
// 256/wave). Per step, acc[g][rt] accumulates A[t]@W AND h@Wh with identical
// fragment layouts; the existing Part LDS reduction then sums k-quarters of
// the WHOLE gate preactivation. xp never touches memory (replaces the
// standalone 161-GFLOP gemm + 336 MB of XP traffic).
// Weights register-resident: Wreg 5x8 frags (160 VGPR) + Hreg 5x4 (80 VGPR).
// Sync protocol byte-identical to R13 (R5-proven, replay-validated).
__global__ __launch_bounds__(256, 1) void lstm_fused(const unsigned short* __restrict__ Abf,
                                                     const float* __restrict__ q,
                                                     const unsigned short* __restrict__ WT,
                                                     const unsigned short* __restrict__ WhT,
                                                     const float* __restrict__ bias,
                                                     const float* __restrict__ c0,
                                                     unsigned short* __restrict__ hb0,
                                                     unsigned short* __restrict__ hb1,
                                                     float* __restrict__ out,
                                                     unsigned* __restrict__ cnts){
  __shared__ float Part[4][5][2][16][20];        // [w][gate][rt][m][b pad20] 51.2 KB
  const int tid  = threadIdx.x;
  const int w    = tid >> 6, lane = tid & 63;
  const int lrow = lane & 15, lhi = lane >> 4;
  const int bt = blockIdx.x >> 5, mc = blockIdx.x & 31;
  const int b0 = bt * 32, m0 = mc * 16;
  unsigned* cnt = cnts + bt * 64;                // per-bt counter, own cacheline

  // ---- register-resident weights ----
  // xp weights: wave w's k-quarter [w*256,(w+1)*256) of all 5 gate col-frags
  bf16x8 Wreg[5][8];
  #pragma unroll
  for (int g = 0; g < 5; ++g)
    #pragma unroll
    for (int c = 0; c < 8; ++c)
      Wreg[g][c] = *reinterpret_cast<const bf16x8*>(
          WT + (long)(g*MM + m0 + lrow)*K1P + w*256 + c*32 + lhi*8);
  // Wh weights: wave w's k-quarter [w*128,(w+1)*128)
  bf16x8 Hreg[5][4];
  #pragma unroll
  for (int g = 0; g < 5; ++g)
    #pragma unroll
    for (int kf = 0; kf < 4; ++kf)
      Hreg[g][kf] = *reinterpret_cast<const bf16x8*>(
          WhT + (long)(g*MM + m0 + lrow)*MM + w*128 + kf*32 + lhi*8);

  // update-phase mapping: 2 states per thread
  const int bl = tid >> 3, mi2 = (tid & 7) * 2;
  const int rt2 = bl >> 4, brow = bl & 15;
  const int gb = b0 + bl, gm = m0 + mi2;
  float cx = c0[(long)gb*MM + gm];
  float cy = c0[(long)gb*MM + gm + 1];

  // bias preload (xp's +b term)
  float bq[5][2];
  #pragma unroll
  for (int g = 0; g < 5; ++g){
    bq[g][0] = bias[g*MM + gm];
    bq[g][1] = bias[g*MM + gm + 1];
  }

  // per-lane A base addresses (t-running); q running offset
  const unsigned short* aB0 = Abf + (long)(b0 + 0*16 + lrow)*K1P + w*256 + lhi*8;
  const unsigned short* aB1 = Abf + (long)(b0 + 1*16 + lrow)*K1P + w*256 + lhi*8;
  const long ASTEP = (long)BB * K1P;             // +256 rows per t
  const long qb0 = (long)gb*MM + gm;
  const long QSTEP = (long)BB*MM;
  float qx = q[qb0], qy = q[qb0 + 1];
  long qo = QSTEP;

  for (int t = 0; t < TT; ++t){
    const unsigned short* hc = (t & 1) ? hb1 : hb0;
    unsigned short*       hn = (t & 1) ? hb0 : hb1;

    // issue A-fragment loads FIRST (16, oldest in queue; L2/MALL-shared
    // across the group since all 32 blocks read the same 64 KB slice)...
    bf16x8 aw[2][8];
    #pragma unroll
    for (int c = 0; c < 8; ++c){
      aw[0][c] = ldg16(aB0 + c*32);
      aw[1][c] = ldg16(aB1 + c*32);
    }
    // ...then h loads (8, youngest), kf-major
    bf16x8 af[2][4];
    #pragma unroll
    for (int kf = 0; kf < 4; ++kf)
      #pragma unroll
      for (int rt = 0; rt < 2; ++rt)
        af[rt][kf] = load_h16(hc + (long)(b0 + rt*16 + lrow)*MM + w*128 + kf*32 + lhi*8);

    // wait for all A (h may still fly), run the xp MFMAs under h latency
    f32x4 acc[5][2] = {};
    __builtin_amdgcn_sched_barrier(0);
    asm volatile("s_waitcnt vmcnt(8)" ::: "memory");
    __builtin_amdgcn_sched_barrier(0);
    #pragma unroll
    for (int c = 0; c < 8; ++c)
      #pragma unroll
      for (int rt = 0; rt < 2; ++rt)
        #pragma unroll
        for (int g = 0; g < 5; ++g)
          acc[g][rt] = __builtin_amdgcn_mfma_f32_16x16x32_bf16(aw[rt][c], Wreg[g][c], acc[g][rt], 0, 0, 0);

    // h part with counted waits (only h loads remain outstanding)
    #pragma unroll
    for (int kf = 0; kf < 4; ++kf){
      __builtin_amdgcn_sched_barrier(0);
      if      (kf == 0) asm volatile("s_waitcnt vmcnt(6)" ::: "memory");
      else if (kf == 1) asm volatile("s_waitcnt vmcnt(4)" ::: "memory");
      else if (kf == 2) asm volatile("s_waitcnt vmcnt(2)" ::: "memory");
      else              asm volatile("s_waitcnt vmcnt(0)" ::: "memory");
      __builtin_amdgcn_sched_barrier(0);
      #pragma unroll
      for (int rt = 0; rt < 2; ++rt)
        #pragma unroll
        for (int g = 0; g < 5; ++g)
          acc[g][rt] = __builtin_amdgcn_mfma_f32_16x16x32_bf16(af[rt][kf], Hreg[g][kf], acc[g][rt], 0, 0, 0);
    }

    // publish k-partials (D: col=m=lrow, row=b=lhi*4+j -> [m][b] contiguous x4)
    #pragma unroll
    for (int g = 0; g < 5; ++g)
      #pragma unroll
      for (int rt = 0; rt < 2; ++rt)
        *reinterpret_cast<f32x4*>(&Part[w][g][rt][lrow][lhi*4]) = acc[g][rt];
    __syncthreads();                               // syncA: Part ready

    // k-reduction + bias -> full gate preactivation for this thread's 2 states
    float gv[5][2];
    #pragma unroll
    for (int g = 0; g < 5; ++g)
      #pragma unroll
      for (int x = 0; x < 2; ++x)
        gv[g][x] = Part[0][g][rt2][mi2+x][brow] + Part[1][g][rt2][mi2+x][brow]
                 + Part[2][g][rt2][mi2+x][brow] + Part[3][g][rt2][mi2+x][brow]
                 + bq[g][x];

    float hx, hy;
    {
      const float i_ = sigmoidf_(gv[0][0]);
      const float fd = sigmoidf_(gv[1][0]);
      const float fl = sigmoidf_(gv[2][0]);
      const float o_ = sigmoidf_(gv[3][0]);
      const float u_ = tanhf_(gv[4][0]);
      const float cn = i_*u_ + fd*qx + fl*cx;
      cx = cn; hx = o_*tanhf_(cn);
    }
    {
      const float i_ = sigmoidf_(gv[0][1]);
      const float fd = sigmoidf_(gv[1][1]);
      const float fl = sigmoidf_(gv[2][1]);
      const float o_ = sigmoidf_(gv[3][1]);
      const float u_ = tanhf_(gv[4][1]);
      const float cn = i_*u_ + fd*qy + fl*cy;
      cy = cn; hy = o_*tanhf_(cn);
    }

    // store h EARLY (MALL scope) so the drain starts sooner
    const unsigned hv = (unsigned)f2bf(hx) | ((unsigned)f2bf(hy) << 16);
    if (t < TT - 1){
      store_h32(hn + (long)gb*MM + gm, hv);
    } else {
      out[(long)gb*1024 + gm]           = hx;
      out[(long)gb*1024 + gm + 1]       = hy;
      out[(long)gb*1024 + 512 + gm]     = cx;
      out[(long)gb*1024 + 512 + gm + 1] = cy;
    }

    // prefetch next step's q (fills the barrier wait); advance A base
    if (t < TT - 1){
      qx = q[qo + qb0];
      qy = q[qo + qb0 + 1];
      qo += QSTEP;
      aB0 += ASTEP; aB1 += ASTEP;
    }

    // per-bt barrier (R5-proven): syncB drains all h stores to MALL before
    // arrive; tid0 polls; syncC broadcasts.
    if (t != TT - 1){
      __syncthreads();                             // syncB
      if (tid == 0){
        __hip_atomic_fetch_add(cnt, 1u, __ATOMIC_RELAXED, __HIP_MEMORY_SCOPE_AGENT);
        const unsigned target = (unsigned)(t + 1) * 32u;
        unsigned spins = 0;
        while (load_coh_u32(cnt) < target){
          __builtin_amdgcn_s_sleep(1);
          if (++spins > (1u << 20)) break;         // safety valve
        }
      }
      __syncthreads();                             // syncC: release all waves
    }
  }
}

extern "C" void kernel_launch(void* const* d_in, const int* in_sizes, int n_in,
                              void* d_out, int out_size, void* d_ws, size_t ws_size,
                              hipStream_t stream){
  (void)in_sizes; (void)n_in; (void)out_size; (void)ws_size;
  const float* word = (const float*)d_in[0];
  const float* tag  = (const float*)d_in[1];
  const float* rel  = (const float*)d_in[2];
  const float* kin  = (const float*)d_in[3];
  const float* q    = (const float*)d_in[4];
  const float* h0   = (const float*)d_in[5];
  const float* c0   = (const float*)d_in[6];
  const float* Ww   = (const float*)d_in[7];
  const float* Wt   = (const float*)d_in[8];
  const float* Wr   = (const float*)d_in[9];
  const float* Wk   = (const float*)d_in[10];
  const float* Wh   = (const float*)d_in[11];
  const float* bias = (const float*)d_in[12];
  float* out = (float*)d_out;

  char* ws = (char*)d_ws;
  size_t off = 0;
  auto alloc = [&](size_t bytes)->void*{
    void* p = ws + off; off = (off + bytes + 255) & ~(size_t)255; return p;
  };
  unsigned short* Abf = (unsigned short*)alloc((size_t)TT*BB*K1P*2);   // 67.1 MB
  unsigned short* WT  = (unsigned short*)alloc((size_t)GG*K1P*2);      // 5.2 MB
  unsigned short* WhT = (unsigned short*)alloc((size_t)GG*MM*2);       // 2.6 MB
  unsigned short* hb0 = (unsigned short*)alloc((size_t)BB*MM*2);
  unsigned short* hb1 = (unsigned short*)alloc((size_t)BB*MM*2);
  unsigned*       cnt = (unsigned*)alloc(8 * 64 * sizeof(unsigned));   // per-bt counters

  hipMemsetAsync(cnt, 0, 8 * 64 * sizeof(unsigned), stream);

  stage_a  <<<dim3((int)(((long)TT*BB*(K1P/8) + 255)/256)), 256, 0, stream>>>(word, tag, rel, kin, Abf);
  stage_wt <<<dim3((int)(((long)GG*K1P + 255)/256)),        256, 0, stream>>>(Ww, Wt, Wr, Wk, WT);
  stage_wht<<<dim3((GG*MM + 255)/256),                      256, 0, stream>>>(Wh, WhT);
  init_h   <<<dim3((BB*MM + 255)/256),                      256, 0, stream>>>(h0, hb0);

  lstm_fused<<<dim3(256), 256, 0, stream>>>(Abf, q, WT, WhT, bias, c0, hb0, hb1, out, cnt);
}